// Round 1
// baseline (3451.833 us; speedup 1.0000x reference)
//
#include <hip/hip_runtime.h>
#include <math.h>

#define S_LEN 2048
#define HD    64
#define QT    16      // query rows per block
#define NT    512     // threads per block
#define NW    8       // waves per block
#define CAP   512     // candidate capacity per row
#define NITER 50      // entmax bisection iterations (reference default)

__device__ __forceinline__ float wave_max(float v) {
#pragma unroll
    for (int off = 32; off >= 1; off >>= 1)
        v = fmaxf(v, __shfl_xor(v, off, 64));
    return v;
}

__device__ __forceinline__ float wave_sum(float v) {
#pragma unroll
    for (int off = 32; off >= 1; off >>= 1)
        v += __shfl_xor(v, off, 64);
    return v;
}

__device__ __forceinline__ float pfun_t(float t, float inv, bool inv2) {
    float u = fmaxf(t, 0.0f);
    return inv2 ? u * u : powf(u, inv);
}

// Register-resident bisection over <= NR*64 candidates held in LDS row cvrow.
template <int NR>
__device__ __forceinline__ void bisect_reg(const float* cvrow, int ncp, int lane,
                                           float tau_lo0, float tau_hi,
                                           float inv, bool inv2,
                                           float& tau_out, float& isum_out) {
    float c[NR];
#pragma unroll
    for (int j = 0; j < NR; ++j) {
        int i = lane + 64 * j;
        c[j] = (i < ncp) ? cvrow[i] : -3.0e38f;
    }
    float tau = tau_lo0;
    float s0 = 0.0f;
#pragma unroll
    for (int j = 0; j < NR; ++j) s0 += pfun_t(c[j] - tau, inv, inv2);
    const float f_lo = wave_sum(s0) - 1.0f;
    float dm = tau_hi - tau_lo0;
    for (int it = 0; it < NITER; ++it) {
        dm *= 0.5f;
        float tm = tau + dm;
        float s = 0.0f;
#pragma unroll
        for (int j = 0; j < NR; ++j) s += pfun_t(c[j] - tm, inv, inv2);
        float fm = wave_sum(s) - 1.0f;
        if (fm * f_lo >= 0.0f) tau = tm;
    }
    float s = 0.0f;
#pragma unroll
    for (int j = 0; j < NR; ++j) s += pfun_t(c[j] - tau, inv, inv2);
    float ssum = wave_sum(s);
    tau_out = tau;
    isum_out = 1.0f / ssum;
}

__global__ __launch_bounds__(NT, 2)
void entmax_attn(const float* __restrict__ Qp, const float* __restrict__ Kp,
                 const float* __restrict__ Vp, const float* __restrict__ alphap,
                 float* __restrict__ outp, float* __restrict__ pattn) {
    __shared__ float          candv[QT][CAP];
    __shared__ unsigned short candi[QT][CAP];
    __shared__ int            ncnt[QT];
    __shared__ float          rmax8[QT][NW];
    __shared__ float          rmxf[QT];
    __shared__ float          taus[QT];
    __shared__ float          isums[QT];
    __shared__ float          redw[NW];

    const int tid  = threadIdx.x;
    const int wv   = tid >> 6;
    const int lane = tid & 63;
    const int bh   = blockIdx.y;
    const int q0   = blockIdx.x * QT;

    const float alpha = alphap[0];
    const float am1   = alpha - 1.0f;
    const float inv   = 1.0f / am1;
    const bool  inv2  = (inv == 2.0f);
    const float xscale = (1.0f / sqrtf((float)HD)) * am1;   // fold score scale * (alpha-1)
    const float gp_d   = powf(1.0f / (float)S_LEN, am1);    // _gp(1/d, alpha)

    if (tid < QT) ncnt[tid] = 0;

    const float* qbase = Qp + ((size_t)bh * S_LEN + q0) * HD;
    const float* kbase = Kp + (size_t)bh * S_LEN * HD;
    const float* vbase = Vp + (size_t)bh * S_LEN * HD;

    // ---- Phase 1: Xa = (Q.K^T * scale * (alpha-1)) held in registers ----
    float xa[QT][4];
#pragma unroll
    for (int r = 0; r < QT; ++r)
#pragma unroll
        for (int kk = 0; kk < 4; ++kk) xa[r][kk] = 0.0f;

    for (int dc = 0; dc < 8; ++dc) {
        float kv[4][8];
#pragma unroll
        for (int kk = 0; kk < 4; ++kk) {
            const float* kp = kbase + ((size_t)(kk * NT + tid)) * HD + dc * 8;
            float4 a = *(const float4*)kp;
            float4 b = *(const float4*)(kp + 4);
            kv[kk][0] = a.x; kv[kk][1] = a.y; kv[kk][2] = a.z; kv[kk][3] = a.w;
            kv[kk][4] = b.x; kv[kk][5] = b.y; kv[kk][6] = b.z; kv[kk][7] = b.w;
        }
#pragma unroll
        for (int r = 0; r < QT; ++r) {
            const float* qp = qbase + r * HD + dc * 8;  // wave-uniform address
            float4 qa = *(const float4*)qp;
            float4 qb = *(const float4*)(qp + 4);
            float qv[8] = {qa.x, qa.y, qa.z, qa.w, qb.x, qb.y, qb.z, qb.w};
#pragma unroll
            for (int kk = 0; kk < 4; ++kk) {
                float a0 = xa[r][kk];
#pragma unroll
                for (int j = 0; j < 8; ++j) a0 = fmaf(qv[j], kv[kk][j], a0);
                xa[r][kk] = a0;
            }
        }
    }
#pragma unroll
    for (int r = 0; r < QT; ++r)
#pragma unroll
        for (int kk = 0; kk < 4; ++kk) xa[r][kk] *= xscale;

    // ---- Phase 2: exact row maxes ----
#pragma unroll
    for (int r = 0; r < QT; ++r) {
        float pm = fmaxf(fmaxf(xa[r][0], xa[r][1]), fmaxf(xa[r][2], xa[r][3]));
        pm = wave_max(pm);
        if (lane == 0) rmax8[r][wv] = pm;
    }
    __syncthreads();
    if (tid < QT) {
        float m = rmax8[tid][0];
#pragma unroll
        for (int w = 1; w < NW; ++w) m = fmaxf(m, rmax8[tid][w]);
        rmxf[tid] = m;
    }
    __syncthreads();

    // ---- Phase 3: candidate compaction (Xa > tau_lo0 can ever be nonzero) ----
#pragma unroll
    for (int r = 0; r < QT; ++r) {
        const float tl0 = rmxf[r] - 1.0f;
#pragma unroll
        for (int kk = 0; kk < 4; ++kk) {
            const float v = xa[r][kk];
            const bool pred = (v > tl0);
            unsigned long long m = __ballot(pred);
            int base = 0;
            if (lane == 0 && m) base = atomicAdd(&ncnt[r], __popcll(m));
            base = __shfl(base, 0, 64);
            if (pred) {
                int pos = base + __popcll(m & ((1ull << lane) - 1ull));
                if (pos < CAP) {
                    candv[r][pos] = v;
                    candi[r][pos] = (unsigned short)(kk * NT + tid);
                }
            }
        }
    }
    __syncthreads();

    // ---- Phase 4: per-wave bisection (wave w owns rows w and w+8) ----
    for (int rr = 0; rr < QT / NW; ++rr) {
        const int row = wv + rr * NW;
        const int nc = ncnt[row];
        if (nc <= CAP) {
            const int ncp = (nc + 7) & ~7;
            for (int i = nc + lane; i < ncp; i += 64) {  // pad to multiple of 8
                candv[row][i] = -3.0e38f;
                candi[row][i] = 0;
            }
            const float mx  = rmxf[row];
            const float tl0 = mx - 1.0f;
            const float th  = mx - gp_d;
            float tau, isum;
            if (ncp <= 256) bisect_reg<4>(&candv[row][0], ncp, lane, tl0, th, inv, inv2, tau, isum);
            else            bisect_reg<8>(&candv[row][0], ncp, lane, tl0, th, inv, inv2, tau, isum);
            if (lane == 0) { taus[row] = tau; isums[row] = isum; }
        }
    }

    // ---- Phase 4b: block-wide fallback for overflow rows (nc > CAP; rare) ----
#pragma unroll
    for (int r = 0; r < QT; ++r) {
        if (ncnt[r] > CAP) {   // uniform condition -> barriers are safe
            const float mx = rmxf[r];
            float tau = mx - 1.0f;
            float s0 = 0.0f;
#pragma unroll
            for (int kk = 0; kk < 4; ++kk) s0 += pfun_t(xa[r][kk] - tau, inv, inv2);
            s0 = wave_sum(s0);
            if (lane == 0) redw[wv] = s0;
            __syncthreads();
            float f_lo = redw[0] + redw[1] + redw[2] + redw[3] +
                         redw[4] + redw[5] + redw[6] + redw[7] - 1.0f;
            __syncthreads();
            float dm = (mx - gp_d) - tau;
            for (int it = 0; it < NITER; ++it) {
                dm *= 0.5f;
                float tm = tau + dm;
                float s = 0.0f;
#pragma unroll
                for (int kk = 0; kk < 4; ++kk) s += pfun_t(xa[r][kk] - tm, inv, inv2);
                s = wave_sum(s);
                if (lane == 0) redw[wv] = s;
                __syncthreads();
                float fm = redw[0] + redw[1] + redw[2] + redw[3] +
                           redw[4] + redw[5] + redw[6] + redw[7] - 1.0f;
                __syncthreads();
                if (fm * f_lo >= 0.0f) tau = tm;
            }
            float s = 0.0f;
#pragma unroll
            for (int kk = 0; kk < 4; ++kk) s += pfun_t(xa[r][kk] - tau, inv, inv2);
            s = wave_sum(s);
            if (lane == 0) redw[wv] = s;
            __syncthreads();
            float ssum = redw[0] + redw[1] + redw[2] + redw[3] +
                         redw[4] + redw[5] + redw[6] + redw[7];
            __syncthreads();
            if (tid == 0) { taus[r] = tau; isums[r] = 1.0f / ssum; }
        }
    }
    __syncthreads();

    // ---- Phase 5: write normalized p_attn (all S entries incl. zeros) ----
    const size_t prow_base = ((size_t)bh * S_LEN + q0) * S_LEN;
#pragma unroll
    for (int r = 0; r < QT; ++r) {
        const float tau  = taus[r];
        const float isum = isums[r];
        float* prow = pattn + prow_base + (size_t)r * S_LEN;
#pragma unroll
        for (int kk = 0; kk < 4; ++kk) {
            float p = pfun_t(xa[r][kk] - tau, inv, inv2) * isum;
            prow[kk * NT + tid] = p;
        }
    }
    __threadfence_block();
    __syncthreads();

    // ---- Phase 6: out = p @ V, sparse over candidates (lane == d) ----
    for (int rr = 0; rr < QT / NW; ++rr) {
        const int row  = wv + rr * NW;
        const int qrow = q0 + row;
        const int nc   = ncnt[row];
        const float tau  = taus[row];
        const float isum = isums[row];
        float oacc = 0.0f;
        if (nc <= CAP) {
            const int ncp = (nc + 7) & ~7;
            for (int i = lane; i < ncp; i += 64)  // candv := unnormalized p
                candv[row][i] = pfun_t(candv[row][i] - tau, inv, inv2);
            for (int i = 0; i < ncp; i += 8) {
#pragma unroll
                for (int u = 0; u < 8; ++u) {
                    oacc = fmaf(candv[row][i + u],
                                vbase[(size_t)candi[row][i + u] * HD + lane], oacc);
                }
            }
            oacc *= isum;
        } else {
            // read back normalized p from global (written above, fenced)
            const float* prow = pattn + ((size_t)bh * S_LEN + qrow) * S_LEN;
            for (int k = 0; k < S_LEN; ++k)
                oacc = fmaf(prow[k], vbase[(size_t)k * HD + lane], oacc);
        }
        outp[((size_t)bh * S_LEN + qrow) * HD + lane] = oacc;
    }
}

extern "C" void kernel_launch(void* const* d_in, const int* in_sizes, int n_in,
                              void* d_out, int out_size, void* d_ws, size_t ws_size,
                              hipStream_t stream) {
    const float* Q = (const float*)d_in[0];
    const float* K = (const float*)d_in[1];
    const float* V = (const float*)d_in[2];
    const float* A = (const float*)d_in[3];
    float* out = (float*)d_out;
    const int BH = in_sizes[0] / (S_LEN * HD);          // 64
    float* p = out + (size_t)BH * S_LEN * HD;           // p_attn follows out
    dim3 grid(S_LEN / QT, BH);
    entmax_attn<<<grid, NT, 0, stream>>>(Q, K, V, A, out, p);
}